// Round 2
// baseline (504.234 us; speedup 1.0000x reference)
//
#include <hip/hip_runtime.h>

#define H     1024
#define IMG   2048
#define MID   512
#define VOCAB 32000
#define NR    576
#define IN1   4096
#define IN2   3072

__device__ __forceinline__ float wave_sum(float v) {
  #pragma unroll
  for (int off = 32; off > 0; off >>= 1) v += __shfl_down(v, off, 64);
  return v;
}
__device__ __forceinline__ float sigf(float x) { return 1.0f / (1.0f + __expf(-x)); }
__device__ __forceinline__ float dot4(float4 a, float4 b) {
  return a.x * b.x + a.y * b.y + a.z * b.z + a.w * b.w;
}

// ---- x1 assembly: h2 copy + emb gather (2048 threads) ----
__global__ void k_x1_copy(const float* __restrict__ h2, const float* __restrict__ emb,
                          const int* __restrict__ w, float* __restrict__ x1) {
  int t = blockIdx.x * 256 + threadIdx.x;
  if (t < H) x1[t] = h2[t];
  else {
    int j = t - H;
    x1[3072 + j] = emb[(long)w[0] * 1024 + j];
  }
}

// ---- vbar: 64 blocks x 9 rows, atomicAdd pre-scaled partials into x1[H..H+IMG) ----
__global__ void k_vbar(const float* __restrict__ V, float* __restrict__ x1) {
  int t = threadIdx.x;
  int r0 = blockIdx.x * 9;
  float s[8];
  #pragma unroll
  for (int j = 0; j < 8; j++) s[j] = 0.f;
  for (int rr = 0; rr < 9; rr++) {
    const float4* row = (const float4*)(V + (long)(r0 + rr) * IMG);
    float4 qa = row[t * 2], qb = row[t * 2 + 1];
    s[0] += qa.x; s[1] += qa.y; s[2] += qa.z; s[3] += qa.w;
    s[4] += qb.x; s[5] += qb.y; s[6] += qb.z; s[7] += qb.w;
  }
  #pragma unroll
  for (int j = 0; j < 8; j++)
    atomicAdd(&x1[H + t * 8 + j], s[j] * (1.0f / 576.0f));
}

// ---- vt init with bias ----
__global__ void k_vt_init(const float* __restrict__ lvb, float* __restrict__ vt) {
  int idx = blockIdx.x * 256 + threadIdx.x;   // 294912
  vt[idx] = lvb[idx & (MID - 1)];
}

// ---- vt GEMM: tile 32r x 128c, split-K z=8 (K-chunk 256), 4x4 reg blocking, atomic out ----
__global__ __launch_bounds__(256) void k_vt_partial(const float* __restrict__ V,
                                                    const float* __restrict__ lvw,
                                                    float* __restrict__ vt) {
  __shared__ float Vs[32][64];
  __shared__ float Ws[64][128];   // [k][m]
  int t = threadIdx.x;
  int m0 = blockIdx.x * 128;
  int r0 = blockIdx.y * 32;
  int z  = blockIdx.z;
  int cg = t & 31, rg = t >> 5;
  float acc[4][4];
  #pragma unroll
  for (int i = 0; i < 4; i++)
    #pragma unroll
    for (int j = 0; j < 4; j++) acc[i][j] = 0.f;

  for (int chunk = 0; chunk < 4; chunk++) {
    int k0 = z * 256 + chunk * 64;
    {
      int r = t >> 3, kc = (t & 7) * 8;
      const float4* p = (const float4*)(V + (long)(r0 + r) * IMG + k0 + kc);
      float4 qa = p[0], qb = p[1];
      *(float4*)&Vs[r][kc]     = qa;
      *(float4*)&Vs[r][kc + 4] = qb;
    }
    #pragma unroll
    for (int jj = 0; jj < 4; jj++) {
      int c = t + 256 * jj;
      int m = c >> 3, kc = (c & 7) * 8;
      const float4* p = (const float4*)(lvw + (long)(m0 + m) * IMG + k0 + kc);
      float4 qa = p[0], qb = p[1];
      Ws[kc + 0][m] = qa.x; Ws[kc + 1][m] = qa.y;
      Ws[kc + 2][m] = qa.z; Ws[kc + 3][m] = qa.w;
      Ws[kc + 4][m] = qb.x; Ws[kc + 5][m] = qb.y;
      Ws[kc + 6][m] = qb.z; Ws[kc + 7][m] = qb.w;
    }
    __syncthreads();
    #pragma unroll
    for (int k4 = 0; k4 < 16; k4++) {
      int k = k4 * 4;
      float4 w0 = *(const float4*)&Ws[k + 0][cg * 4];
      float4 w1 = *(const float4*)&Ws[k + 1][cg * 4];
      float4 w2 = *(const float4*)&Ws[k + 2][cg * 4];
      float4 w3 = *(const float4*)&Ws[k + 3][cg * 4];
      #pragma unroll
      for (int i = 0; i < 4; i++) {
        float4 vv = *(const float4*)&Vs[rg * 4 + i][k];
        acc[i][0] += vv.x * w0.x + vv.y * w1.x + vv.z * w2.x + vv.w * w3.x;
        acc[i][1] += vv.x * w0.y + vv.y * w1.y + vv.z * w2.y + vv.w * w3.y;
        acc[i][2] += vv.x * w0.z + vv.y * w1.z + vv.z * w2.z + vv.w * w3.z;
        acc[i][3] += vv.x * w0.w + vv.y * w1.w + vv.z * w2.w + vv.w * w3.w;
      }
    }
    __syncthreads();
  }
  #pragma unroll
  for (int i = 0; i < 4; i++)
    #pragma unroll
    for (int j = 0; j < 4; j++)
      atomicAdd(&vt[(long)(r0 + rg * 4 + i) * MID + m0 + cg * 4 + j], acc[i][j]);
}

// ---- LSTM1 gates: wave-per-row, 4 rows/block ----
__global__ void k_lstm1_gates(const float* __restrict__ Wih, const float* __restrict__ Whh,
                              const float* __restrict__ bih, const float* __restrict__ bhh,
                              const float* __restrict__ x1, const float* __restrict__ h1,
                              float* __restrict__ g1) {
  int w = threadIdx.x >> 6, l = threadIdx.x & 63;
  int row = blockIdx.x * 4 + w;
  const float4* W4  = (const float4*)(Wih + (long)row * IN1);
  const float4* Wh4 = (const float4*)(Whh + (long)row * H);
  const float4* X4  = (const float4*)x1;
  const float4* H14 = (const float4*)h1;
  float acc = 0.f;
  #pragma unroll
  for (int c = 0; c < 16; c++) {
    int idx = c * 64 + l;
    acc += dot4(W4[idx], X4[idx]);
  }
  #pragma unroll
  for (int c = 0; c < 4; c++) {
    int idx = c * 64 + l;
    acc += dot4(Wh4[idx], H14[idx]);
  }
  acc = wave_sum(acc);
  if (l == 0) g1[row] = acc + bih[row] + bhh[row];
}

// ---- shared LSTM elementwise ----
__global__ void k_lstm_elem(const float* __restrict__ g, const float* __restrict__ c_in,
                            float* __restrict__ h_ws, float* __restrict__ out_h,
                            float* __restrict__ out_c) {
  int k = blockIdx.x * 256 + threadIdx.x;   // 1024 threads
  float i  = sigf(g[k]);
  float f  = sigf(g[k + H]);
  float gg = tanhf(g[k + 2 * H]);
  float o  = sigf(g[k + 3 * H]);
  float c  = f * c_in[k] + i * gg;
  float h  = o * tanhf(c);
  h_ws[k]  = h;
  out_h[k] = h;
  out_c[k] = c;
}

// ---- h1t = lh_w @ h1n + lh_b ----
__global__ void k_h1t(const float* __restrict__ lhw, const float* __restrict__ lhb,
                      const float* __restrict__ h1n, float* __restrict__ h1t) {
  int w = threadIdx.x >> 6, l = threadIdx.x & 63;
  int row = blockIdx.x * 4 + w;   // 512 rows
  const float4* W4 = (const float4*)(lhw + (long)row * H);
  const float4* X4 = (const float4*)h1n;
  float acc = 0.f;
  #pragma unroll
  for (int c = 0; c < 4; c++) {
    int idx = c * 64 + l;
    acc += dot4(W4[idx], X4[idx]);
  }
  acc = wave_sum(acc);
  if (l == 0) h1t[row] = acc + lhb[row];
}

// ---- attention logits: wave-per-region ----
__global__ void k_att(const float* __restrict__ vt, const float* __restrict__ h1t,
                      const float* __restrict__ attw, const float* __restrict__ attb,
                      float* __restrict__ logits) {
  int w = threadIdx.x >> 6, l = threadIdx.x & 63;
  int row = blockIdx.x * 4 + w;   // 576 rows
  const float4* vr = (const float4*)(vt + (long)row * MID);
  const float4* A4 = (const float4*)attw;
  const float4* T4 = (const float4*)h1t;
  float4 a0 = A4[2 * l], a1 = A4[2 * l + 1];
  float4 v0 = vr[2 * l], v1 = vr[2 * l + 1];
  float4 t0 = T4[2 * l], t1 = T4[2 * l + 1];
  float acc = tanhf(v0.x + t0.x) * a0.x + tanhf(v0.y + t0.y) * a0.y
            + tanhf(v0.z + t0.z) * a0.z + tanhf(v0.w + t0.w) * a0.w
            + tanhf(v1.x + t1.x) * a1.x + tanhf(v1.y + t1.y) * a1.y
            + tanhf(v1.z + t1.z) * a1.z + tanhf(v1.w + t1.w) * a1.w;
  acc = wave_sum(acc);
  if (l == 0) logits[row] = acc + attb[0];
}

// ---- softmax over 576 (single block, 1024 threads) ----
__global__ void k_softmax(const float* __restrict__ logits, float* __restrict__ a) {
  __shared__ float red[16];
  int t = threadIdx.x;
  int wv = t >> 6, l = t & 63;
  float x = (t < NR) ? logits[t] : -3.0e38f;
  float m = x;
  #pragma unroll
  for (int off = 32; off > 0; off >>= 1) m = fmaxf(m, __shfl_down(m, off, 64));
  if (l == 0) red[wv] = m;
  __syncthreads();
  if (t == 0) {
    float mm = red[0];
    for (int i = 1; i < 16; i++) mm = fmaxf(mm, red[i]);
    red[0] = mm;
  }
  __syncthreads();
  float bmax = red[0];
  float e = (t < NR) ? __expf(x - bmax) : 0.f;
  __syncthreads();
  float s = wave_sum(e);
  if (l == 0) red[wv] = s;
  __syncthreads();
  if (t == 0) {
    float ss = 0.f;
    for (int i = 0; i < 16; i++) ss += red[i];
    red[0] = ss;
  }
  __syncthreads();
  float bsum = red[0];
  if (t < NR) a[t] = e / bsum;
}

// ---- v = sum_r a[r] * V[r,:]  (64 blocks x 9 rows, atomic) ----
__global__ void k_wv(const float* __restrict__ V, const float* __restrict__ a,
                     float* __restrict__ v) {
  int t = threadIdx.x;
  int r0 = blockIdx.x * 9;
  float s[8];
  #pragma unroll
  for (int j = 0; j < 8; j++) s[j] = 0.f;
  for (int rr = 0; rr < 9; rr++) {
    float ar = a[r0 + rr];
    const float4* row = (const float4*)(V + (long)(r0 + rr) * IMG);
    float4 qa = row[t * 2], qb = row[t * 2 + 1];
    s[0] += ar * qa.x; s[1] += ar * qa.y; s[2] += ar * qa.z; s[3] += ar * qa.w;
    s[4] += ar * qb.x; s[5] += ar * qb.y; s[6] += ar * qb.z; s[7] += ar * qb.w;
  }
  #pragma unroll
  for (int j = 0; j < 8; j++) atomicAdd(&v[t * 8 + j], s[j]);
}

// ---- LSTM2 gates ----
__global__ void k_lstm2_gates(const float* __restrict__ Wih, const float* __restrict__ Whh,
                              const float* __restrict__ bih, const float* __restrict__ bhh,
                              const float* __restrict__ v, const float* __restrict__ h1n,
                              const float* __restrict__ h2, float* __restrict__ g2) {
  int w = threadIdx.x >> 6, l = threadIdx.x & 63;
  int row = blockIdx.x * 4 + w;
  const float4* W4  = (const float4*)(Wih + (long)row * IN2);
  const float4* Wh4 = (const float4*)(Whh + (long)row * H);
  const float4* Vv4 = (const float4*)v;
  const float4* H1n = (const float4*)h1n;
  const float4* H24 = (const float4*)h2;
  float acc = 0.f;
  #pragma unroll
  for (int c = 0; c < 8; c++) {           // v part (cols 0..2047)
    int idx = c * 64 + l;
    acc += dot4(W4[idx], Vv4[idx]);
  }
  #pragma unroll
  for (int c = 0; c < 4; c++) {           // h1n part (cols 2048..3071)
    int idx = c * 64 + l;
    acc += dot4(W4[512 + idx], H1n[idx]);
  }
  #pragma unroll
  for (int c = 0; c < 4; c++) {           // Whh2 * h2
    int idx = c * 64 + l;
    acc += dot4(Wh4[idx], H24[idx]);
  }
  acc = wave_sum(acc);
  if (l == 0) g2[row] = acc + bih[row] + bhh[row];
}

// ---- output logits: wave-per-row over 32000 ----
__global__ void k_out(const float* __restrict__ linw, const float* __restrict__ linb,
                      const float* __restrict__ h2n, float* __restrict__ o) {
  int w = threadIdx.x >> 6, l = threadIdx.x & 63;
  int row = blockIdx.x * 4 + w;
  const float4* W4 = (const float4*)(linw + (long)row * H);
  const float4* X4 = (const float4*)h2n;
  float acc = 0.f;
  #pragma unroll
  for (int c = 0; c < 4; c++) {
    int idx = c * 64 + l;
    acc += dot4(W4[idx], X4[idx]);
  }
  acc = wave_sum(acc);
  if (l == 0) o[row] = acc + linb[row];
}

extern "C" void kernel_launch(void* const* d_in, const int* in_sizes, int n_in,
                              void* d_out, int out_size, void* d_ws, size_t ws_size,
                              hipStream_t stream) {
  const float* V    = (const float*)d_in[0];
  const int*   w    = (const int*)d_in[1];
  const float* h1   = (const float*)d_in[2];
  const float* c1   = (const float*)d_in[3];
  const float* h2   = (const float*)d_in[4];
  const float* c2   = (const float*)d_in[5];
  const float* emb  = (const float*)d_in[6];
  const float* Wih1 = (const float*)d_in[7];
  const float* Whh1 = (const float*)d_in[8];
  const float* bih1 = (const float*)d_in[9];
  const float* bhh1 = (const float*)d_in[10];
  const float* Wih2 = (const float*)d_in[11];
  const float* Whh2 = (const float*)d_in[12];
  const float* bih2 = (const float*)d_in[13];
  const float* bhh2 = (const float*)d_in[14];
  const float* lvw  = (const float*)d_in[15];
  const float* lvb  = (const float*)d_in[16];
  const float* lhw  = (const float*)d_in[17];
  const float* lhb  = (const float*)d_in[18];
  const float* attw = (const float*)d_in[19];
  const float* attb = (const float*)d_in[20];
  const float* linw = (const float*)d_in[21];
  const float* linb = (const float*)d_in[22];

  float* ws     = (float*)d_ws;
  float* x1     = ws;            // 4096
  float* g1     = ws + 4096;     // 4096
  float* h1n    = ws + 8192;     // 1024
  float* h1t    = ws + 9216;     // 512
  float* logits = ws + 9728;     // 576
  float* a      = ws + 10304;    // 576
  float* v      = ws + 10880;    // 2048
  float* g2     = ws + 12928;    // 4096
  float* h2n    = ws + 17024;    // 1024
  float* vt     = ws + 18048;    // 294912  (ends 312960 floats = 1.22 MB)

  float* out    = (float*)d_out;
  float* out_o  = out;
  float* out_h1 = out + VOCAB;
  float* out_c1 = out + VOCAB + H;
  float* out_h2 = out + VOCAB + 2 * H;
  float* out_c2 = out + VOCAB + 3 * H;

  hipMemsetAsync(x1 + H, 0, IMG * sizeof(float), stream);
  hipMemsetAsync(v, 0, IMG * sizeof(float), stream);

  k_vt_init<<<1152, 256, 0, stream>>>(lvb, vt);
  k_x1_copy<<<8, 256, 0, stream>>>(h2, emb, w, x1);
  k_vbar<<<64, 256, 0, stream>>>(V, x1);
  k_vt_partial<<<dim3(4, 18, 8), 256, 0, stream>>>(V, lvw, vt);
  k_lstm1_gates<<<1024, 256, 0, stream>>>(Wih1, Whh1, bih1, bhh1, x1, h1, g1);
  k_lstm_elem<<<4, 256, 0, stream>>>(g1, c1, h1n, out_h1, out_c1);
  k_h1t<<<128, 256, 0, stream>>>(lhw, lhb, h1n, h1t);
  k_att<<<144, 256, 0, stream>>>(vt, h1t, attw, attb, logits);
  k_softmax<<<1, 1024, 0, stream>>>(logits, a);
  k_wv<<<64, 256, 0, stream>>>(V, a, v);
  k_lstm2_gates<<<1024, 256, 0, stream>>>(Wih2, Whh2, bih2, bhh2, v, h1n, h2, g2);
  k_lstm_elem<<<4, 256, 0, stream>>>(g2, c2, h2n, out_h2, out_c2);
  k_out<<<8000, 256, 0, stream>>>(linw, linb, h2n, out_o);
}

// Round 3
// 450.551 us; speedup vs baseline: 1.1191x; 1.1191x over previous
//
#include <hip/hip_runtime.h>

#define H     1024
#define IMG   2048
#define MID   512
#define VOCAB 32000
#define NR    576
#define IN1   4096
#define IN2   3072

typedef unsigned short u16;
typedef unsigned int u32;
typedef __attribute__((ext_vector_type(8))) short short8;
typedef __attribute__((ext_vector_type(4))) float f32x4;

__device__ __forceinline__ float wave_sum(float v) {
  #pragma unroll
  for (int off = 32; off > 0; off >>= 1) v += __shfl_down(v, off, 64);
  return v;
}
__device__ __forceinline__ float sigf(float x) { return 1.0f / (1.0f + __expf(-x)); }
__device__ __forceinline__ float dot4(float4 a, float4 b) {
  return a.x * b.x + a.y * b.y + a.z * b.z + a.w * b.w;
}
__device__ __forceinline__ u32 f2bfbits(float f) {  // RNE
  union { float f; u32 i; } c; c.f = f;
  return (c.i + 0x7fffu + ((c.i >> 16) & 1u)) >> 16;
}

// ---- convert V (1179648) + lvw (1048576) fp32 -> bf16 scratch ----
#define VN  (NR * IMG)        // 1179648
#define WN  (MID * IMG)       // 1048576
__global__ void k_cvt(const float* __restrict__ V, const float* __restrict__ lvw,
                      u16* __restrict__ Vbf, u16* __restrict__ Wbf) {
  long i8 = (long)(blockIdx.x * 256 + threadIdx.x) * 8;   // 1088 blocks covers 2228224
  const float* src;
  u16* dst;
  long off;
  if (i8 < VN) { src = V; dst = Vbf; off = i8; }
  else         { src = lvw; dst = Wbf; off = i8 - VN; }
  float4 qa = *(const float4*)(src + off);
  float4 qb = *(const float4*)(src + off + 4);
  u32 p0 = f2bfbits(qa.x) | (f2bfbits(qa.y) << 16);
  u32 p1 = f2bfbits(qa.z) | (f2bfbits(qa.w) << 16);
  u32 p2 = f2bfbits(qb.x) | (f2bfbits(qb.y) << 16);
  u32 p3 = f2bfbits(qb.z) | (f2bfbits(qb.w) << 16);
  uint4 st = make_uint4(p0, p1, p2, p3);
  *(uint4*)(dst + off) = st;
}

// ---- vt GEMM via MFMA bf16: grid (9,8,4); block 64x64 tile, 2x2 waves of 32x32 ----
// A[m][k]=V[m][k]; B[k][n]=lvw[n][k]. Frag: lane holds row (lane&15), k = (lane>>4)*8+j.
__global__ __launch_bounds__(256) void k_vt_mfma(const u16* __restrict__ Vbf,
                                                 const u16* __restrict__ Wbf,
                                                 float* __restrict__ vtp) {
  int t = threadIdx.x;
  int wave = t >> 6, lane = t & 63;
  int wm = wave >> 1, wn = wave & 1;
  int m0 = blockIdx.x * 64 + wm * 32;
  int n0 = blockIdx.y * 64 + wn * 32;
  int z  = blockIdx.z;                 // 0..3, K-chunk 512
  int ri = lane & 15, quad = lane >> 4;
  const u16* aptr0 = Vbf + (long)(m0 + ri) * IMG + z * 512 + quad * 8;
  const u16* aptr1 = aptr0 + 16 * IMG;
  const u16* bptr0 = Wbf + (long)(n0 + ri) * IMG + z * 512 + quad * 8;
  const u16* bptr1 = bptr0 + 16 * IMG;
  f32x4 acc00 = {0.f, 0.f, 0.f, 0.f};
  f32x4 acc01 = {0.f, 0.f, 0.f, 0.f};
  f32x4 acc10 = {0.f, 0.f, 0.f, 0.f};
  f32x4 acc11 = {0.f, 0.f, 0.f, 0.f};
  #pragma unroll 4
  for (int ks = 0; ks < 16; ks++) {
    int ko = ks * 32;
    short8 a0 = *(const short8*)(aptr0 + ko);
    short8 a1 = *(const short8*)(aptr1 + ko);
    short8 b0 = *(const short8*)(bptr0 + ko);
    short8 b1 = *(const short8*)(bptr1 + ko);
    acc00 = __builtin_amdgcn_mfma_f32_16x16x32_bf16(a0, b0, acc00, 0, 0, 0);
    acc01 = __builtin_amdgcn_mfma_f32_16x16x32_bf16(a0, b1, acc01, 0, 0, 0);
    acc10 = __builtin_amdgcn_mfma_f32_16x16x32_bf16(a1, b0, acc10, 0, 0, 0);
    acc11 = __builtin_amdgcn_mfma_f32_16x16x32_bf16(a1, b1, acc11, 0, 0, 0);
  }
  // D mapping: col = lane&15, row = quad*4 + reg
  float* base = vtp + (long)z * (NR * MID);
  #pragma unroll
  for (int r = 0; r < 4; r++) {
    int row = quad * 4 + r;
    base[(long)(m0 + row) * MID + n0 + ri]           = acc00[r];
    base[(long)(m0 + row) * MID + n0 + 16 + ri]      = acc01[r];
    base[(long)(m0 + 16 + row) * MID + n0 + ri]      = acc10[r];
    base[(long)(m0 + 16 + row) * MID + n0 + 16 + ri] = acc11[r];
  }
}

// ---- vt = sum_z vtp + bias ----
__global__ void k_vt_reduce(const float* __restrict__ vtp, const float* __restrict__ lvb,
                            float* __restrict__ vt) {
  int idx = blockIdx.x * 256 + threadIdx.x;   // 294912
  float s = lvb[idx & (MID - 1)];
  #pragma unroll
  for (int z = 0; z < 4; z++) s += vtp[(long)z * (NR * MID) + idx];
  vt[idx] = s;
}

// ---- x1 assembly: h2 copy + emb gather ----
__global__ void k_x1_copy(const float* __restrict__ h2, const float* __restrict__ emb,
                          const int* __restrict__ w, float* __restrict__ x1) {
  int t = blockIdx.x * 256 + threadIdx.x;
  if (t < H) x1[t] = h2[t];
  else {
    int j = t - H;
    x1[3072 + j] = emb[(long)w[0] * 1024 + j];
  }
}

// ---- vbar ----
__global__ void k_vbar(const float* __restrict__ V, float* __restrict__ x1) {
  int t = threadIdx.x;
  int r0 = blockIdx.x * 9;
  float s[8];
  #pragma unroll
  for (int j = 0; j < 8; j++) s[j] = 0.f;
  for (int rr = 0; rr < 9; rr++) {
    const float4* row = (const float4*)(V + (long)(r0 + rr) * IMG);
    float4 qa = row[t * 2], qb = row[t * 2 + 1];
    s[0] += qa.x; s[1] += qa.y; s[2] += qa.z; s[3] += qa.w;
    s[4] += qb.x; s[5] += qb.y; s[6] += qb.z; s[7] += qb.w;
  }
  #pragma unroll
  for (int j = 0; j < 8; j++)
    atomicAdd(&x1[H + t * 8 + j], s[j] * (1.0f / 576.0f));
}

// ---- LSTM1 gates ----
__global__ void k_lstm1_gates(const float* __restrict__ Wih, const float* __restrict__ Whh,
                              const float* __restrict__ bih, const float* __restrict__ bhh,
                              const float* __restrict__ x1, const float* __restrict__ h1,
                              float* __restrict__ g1) {
  int w = threadIdx.x >> 6, l = threadIdx.x & 63;
  int row = blockIdx.x * 4 + w;
  const float4* W4  = (const float4*)(Wih + (long)row * IN1);
  const float4* Wh4 = (const float4*)(Whh + (long)row * H);
  const float4* X4  = (const float4*)x1;
  const float4* H14 = (const float4*)h1;
  float acc = 0.f;
  #pragma unroll
  for (int c = 0; c < 16; c++) {
    int idx = c * 64 + l;
    acc += dot4(W4[idx], X4[idx]);
  }
  #pragma unroll
  for (int c = 0; c < 4; c++) {
    int idx = c * 64 + l;
    acc += dot4(Wh4[idx], H14[idx]);
  }
  acc = wave_sum(acc);
  if (l == 0) g1[row] = acc + bih[row] + bhh[row];
}

// ---- LSTM elementwise ----
__global__ void k_lstm_elem(const float* __restrict__ g, const float* __restrict__ c_in,
                            float* __restrict__ h_ws, float* __restrict__ out_h,
                            float* __restrict__ out_c) {
  int k = blockIdx.x * 256 + threadIdx.x;
  float i  = sigf(g[k]);
  float f  = sigf(g[k + H]);
  float gg = tanhf(g[k + 2 * H]);
  float o  = sigf(g[k + 3 * H]);
  float c  = f * c_in[k] + i * gg;
  float h  = o * tanhf(c);
  h_ws[k]  = h;
  out_h[k] = h;
  out_c[k] = c;
}

// ---- h1t ----
__global__ void k_h1t(const float* __restrict__ lhw, const float* __restrict__ lhb,
                      const float* __restrict__ h1n, float* __restrict__ h1t) {
  int w = threadIdx.x >> 6, l = threadIdx.x & 63;
  int row = blockIdx.x * 4 + w;
  const float4* W4 = (const float4*)(lhw + (long)row * H);
  const float4* X4 = (const float4*)h1n;
  float acc = 0.f;
  #pragma unroll
  for (int c = 0; c < 4; c++) {
    int idx = c * 64 + l;
    acc += dot4(W4[idx], X4[idx]);
  }
  acc = wave_sum(acc);
  if (l == 0) h1t[row] = acc + lhb[row];
}

// ---- attention logits ----
__global__ void k_att(const float* __restrict__ vt, const float* __restrict__ h1t,
                      const float* __restrict__ attw, const float* __restrict__ attb,
                      float* __restrict__ logits) {
  int w = threadIdx.x >> 6, l = threadIdx.x & 63;
  int row = blockIdx.x * 4 + w;
  const float4* vr = (const float4*)(vt + (long)row * MID);
  const float4* A4 = (const float4*)attw;
  const float4* T4 = (const float4*)h1t;
  float4 a0 = A4[2 * l], a1 = A4[2 * l + 1];
  float4 v0 = vr[2 * l], v1 = vr[2 * l + 1];
  float4 t0 = T4[2 * l], t1 = T4[2 * l + 1];
  float acc = tanhf(v0.x + t0.x) * a0.x + tanhf(v0.y + t0.y) * a0.y
            + tanhf(v0.z + t0.z) * a0.z + tanhf(v0.w + t0.w) * a0.w
            + tanhf(v1.x + t1.x) * a1.x + tanhf(v1.y + t1.y) * a1.y
            + tanhf(v1.z + t1.z) * a1.z + tanhf(v1.w + t1.w) * a1.w;
  acc = wave_sum(acc);
  if (l == 0) logits[row] = acc + attb[0];
}

// ---- softmax over 576 ----
__global__ void k_softmax(const float* __restrict__ logits, float* __restrict__ a) {
  __shared__ float red[16];
  int t = threadIdx.x;
  int wv = t >> 6, l = t & 63;
  float x = (t < NR) ? logits[t] : -3.0e38f;
  float m = x;
  #pragma unroll
  for (int off = 32; off > 0; off >>= 1) m = fmaxf(m, __shfl_down(m, off, 64));
  if (l == 0) red[wv] = m;
  __syncthreads();
  if (t == 0) {
    float mm = red[0];
    for (int i = 1; i < 16; i++) mm = fmaxf(mm, red[i]);
    red[0] = mm;
  }
  __syncthreads();
  float bmax = red[0];
  float e = (t < NR) ? __expf(x - bmax) : 0.f;
  __syncthreads();
  float s = wave_sum(e);
  if (l == 0) red[wv] = s;
  __syncthreads();
  if (t == 0) {
    float ss = 0.f;
    for (int i = 0; i < 16; i++) ss += red[i];
    red[0] = ss;
  }
  __syncthreads();
  float bsum = red[0];
  if (t < NR) a[t] = e / bsum;
}

// ---- v = sum_r a[r] * V[r,:] ----
__global__ void k_wv(const float* __restrict__ V, const float* __restrict__ a,
                     float* __restrict__ v) {
  int t = threadIdx.x;
  int r0 = blockIdx.x * 9;
  float s[8];
  #pragma unroll
  for (int j = 0; j < 8; j++) s[j] = 0.f;
  for (int rr = 0; rr < 9; rr++) {
    float ar = a[r0 + rr];
    const float4* row = (const float4*)(V + (long)(r0 + rr) * IMG);
    float4 qa = row[t * 2], qb = row[t * 2 + 1];
    s[0] += ar * qa.x; s[1] += ar * qa.y; s[2] += ar * qa.z; s[3] += ar * qa.w;
    s[4] += ar * qb.x; s[5] += ar * qb.y; s[6] += ar * qb.z; s[7] += ar * qb.w;
  }
  #pragma unroll
  for (int j = 0; j < 8; j++) atomicAdd(&v[t * 8 + j], s[j]);
}

// ---- LSTM2 gates ----
__global__ void k_lstm2_gates(const float* __restrict__ Wih, const float* __restrict__ Whh,
                              const float* __restrict__ bih, const float* __restrict__ bhh,
                              const float* __restrict__ v, const float* __restrict__ h1n,
                              const float* __restrict__ h2, float* __restrict__ g2) {
  int w = threadIdx.x >> 6, l = threadIdx.x & 63;
  int row = blockIdx.x * 4 + w;
  const float4* W4  = (const float4*)(Wih + (long)row * IN2);
  const float4* Wh4 = (const float4*)(Whh + (long)row * H);
  const float4* Vv4 = (const float4*)v;
  const float4* H1n = (const float4*)h1n;
  const float4* H24 = (const float4*)h2;
  float acc = 0.f;
  #pragma unroll
  for (int c = 0; c < 8; c++) {
    int idx = c * 64 + l;
    acc += dot4(W4[idx], Vv4[idx]);
  }
  #pragma unroll
  for (int c = 0; c < 4; c++) {
    int idx = c * 64 + l;
    acc += dot4(W4[512 + idx], H1n[idx]);
  }
  #pragma unroll
  for (int c = 0; c < 4; c++) {
    int idx = c * 64 + l;
    acc += dot4(Wh4[idx], H24[idx]);
  }
  acc = wave_sum(acc);
  if (l == 0) g2[row] = acc + bih[row] + bhh[row];
}

// ---- output logits ----
__global__ void k_out(const float* __restrict__ linw, const float* __restrict__ linb,
                      const float* __restrict__ h2n, float* __restrict__ o) {
  int w = threadIdx.x >> 6, l = threadIdx.x & 63;
  int row = blockIdx.x * 4 + w;
  const float4* W4 = (const float4*)(linw + (long)row * H);
  const float4* X4 = (const float4*)h2n;
  float acc = 0.f;
  #pragma unroll
  for (int c = 0; c < 4; c++) {
    int idx = c * 64 + l;
    acc += dot4(W4[idx], X4[idx]);
  }
  acc = wave_sum(acc);
  if (l == 0) o[row] = acc + linb[row];
}

extern "C" void kernel_launch(void* const* d_in, const int* in_sizes, int n_in,
                              void* d_out, int out_size, void* d_ws, size_t ws_size,
                              hipStream_t stream) {
  const float* V    = (const float*)d_in[0];
  const int*   w    = (const int*)d_in[1];
  const float* h1   = (const float*)d_in[2];
  const float* c1   = (const float*)d_in[3];
  const float* h2   = (const float*)d_in[4];
  const float* c2   = (const float*)d_in[5];
  const float* emb  = (const float*)d_in[6];
  const float* Wih1 = (const float*)d_in[7];
  const float* Whh1 = (const float*)d_in[8];
  const float* bih1 = (const float*)d_in[9];
  const float* bhh1 = (const float*)d_in[10];
  const float* Wih2 = (const float*)d_in[11];
  const float* Whh2 = (const float*)d_in[12];
  const float* bih2 = (const float*)d_in[13];
  const float* bhh2 = (const float*)d_in[14];
  const float* lvw  = (const float*)d_in[15];
  const float* lvb  = (const float*)d_in[16];
  const float* lhw  = (const float*)d_in[17];
  const float* lhb  = (const float*)d_in[18];
  const float* attw = (const float*)d_in[19];
  const float* attb = (const float*)d_in[20];
  const float* linw = (const float*)d_in[21];
  const float* linb = (const float*)d_in[22];

  float* ws     = (float*)d_ws;
  float* x1     = ws;              // 4096
  float* g1     = ws + 4096;       // 4096
  float* h1n    = ws + 8192;       // 1024
  float* h1t    = ws + 9216;       // 512
  float* logits = ws + 9728;       // 576
  float* a      = ws + 10304;      // 576
  float* v      = ws + 10880;      // 2048
  float* g2     = ws + 12928;      // 4096
  float* h2n    = ws + 17024;      // 1024
  float* vt     = ws + 18048;      // 294912
  float* vtp    = ws + 312960;     // 4 * 294912 = 1179648
  u16*   Vbf    = (u16*)(ws + 1492608);        // 1179648 u16
  u16*   Wbf    = Vbf + VN;                    // 1048576 u16  (total ws ~10.4 MB)

  float* out    = (float*)d_out;
  float* out_o  = out;
  float* out_h1 = out + VOCAB;
  float* out_c1 = out + VOCAB + H;
  float* out_h2 = out + VOCAB + 2 * H;
  float* out_c2 = out + VOCAB + 3 * H;

  hipMemsetAsync(x1 + H, 0, IMG * sizeof(float), stream);
  hipMemsetAsync(v, 0, IMG * sizeof(float), stream);

  k_cvt<<<1088, 256, 0, stream>>>(V, lvw, Vbf, Wbf);
  k_x1_copy<<<8, 256, 0, stream>>>(h2, emb, w, x1);
  k_vbar<<<64, 256, 0, stream>>>(V, x1);
  k_vt_mfma<<<dim3(9, 8, 4), 256, 0, stream>>>(Vbf, Wbf, vtp);
  k_vt_reduce<<<1152, 256, 0, stream>>>(vtp, lvb, vt);
  k_lstm1_gates<<<1024, 256, 0, stream>>>(Wih1, Whh1, bih1, bhh1, x1, h1, g1);
  k_lstm_elem<<<4, 256, 0, stream>>>(g1, c1, h1n, out_h1, out_c1);
  k_h1t<<<128, 256, 0, stream>>>(lhw, lhb, h1n, h1t);
  k_att<<<144, 256, 0, stream>>>(vt, h1t, attw, attb, logits);
  k_softmax<<<1, 1024, 0, stream>>>(logits, a);
  k_wv<<<64, 256, 0, stream>>>(V, a, v);
  k_lstm2_gates<<<1024, 256, 0, stream>>>(Wih2, Whh2, bih2, bhh2, v, h1n, h2, g2);
  k_lstm_elem<<<4, 256, 0, stream>>>(g2, c2, h2n, out_h2, out_c2);
  k_out<<<8000, 256, 0, stream>>>(linw, linb, h2n, out_o);
}

// Round 4
// 439.972 us; speedup vs baseline: 1.1461x; 1.0240x over previous
//
#include <hip/hip_runtime.h>

#define H     1024
#define IMG   2048
#define MID   512
#define VOCAB 32000
#define NR    576
#define IN1   4096
#define IN2   3072
#define VN    (NR * IMG)        // 1179648
#define WN    (MID * IMG)       // 1048576

typedef unsigned short u16;
typedef unsigned int u32;
typedef __attribute__((ext_vector_type(8))) short short8;
typedef __attribute__((ext_vector_type(4))) float f32x4;

__device__ __forceinline__ float wave_sum(float v) {
  #pragma unroll
  for (int off = 32; off > 0; off >>= 1) v += __shfl_down(v, off, 64);
  return v;
}
__device__ __forceinline__ float sigf(float x) { return 1.0f / (1.0f + __expf(-x)); }
__device__ __forceinline__ float dot4(float4 a, float4 b) {
  return a.x * b.x + a.y * b.y + a.z * b.z + a.w * b.w;
}
__device__ __forceinline__ u32 f2bfbits(float f) {  // RNE
  union { float f; u32 i; } c; c.f = f;
  return (c.i + 0x7fffu + ((c.i >> 16) & 1u)) >> 16;
}

// ---- prep: blocks [0,1088) cvt V+lvw->bf16; [1088,1096) x1 h2/emb; [1096,1160) vbar ----
__global__ __launch_bounds__(256) void k_prep(const float* __restrict__ V,
                                              const float* __restrict__ lvw,
                                              const float* __restrict__ h2,
                                              const float* __restrict__ emb,
                                              const int* __restrict__ w,
                                              u16* __restrict__ Vbf, u16* __restrict__ Wbf,
                                              float* __restrict__ x1) {
  int b = blockIdx.x;
  int t = threadIdx.x;
  if (b < 1088) {
    long i8 = (long)(b * 256 + t) * 8;   // covers 2228224 = VN + WN
    const float* src; u16* dst; long off;
    if (i8 < VN) { src = V; dst = Vbf; off = i8; }
    else         { src = lvw; dst = Wbf; off = i8 - VN; }
    float4 qa = *(const float4*)(src + off);
    float4 qb = *(const float4*)(src + off + 4);
    u32 p0 = f2bfbits(qa.x) | (f2bfbits(qa.y) << 16);
    u32 p1 = f2bfbits(qa.z) | (f2bfbits(qa.w) << 16);
    u32 p2 = f2bfbits(qb.x) | (f2bfbits(qb.y) << 16);
    u32 p3 = f2bfbits(qb.z) | (f2bfbits(qb.w) << 16);
    *(uint4*)(dst + off) = make_uint4(p0, p1, p2, p3);
  } else if (b < 1096) {
    int tt = (b - 1088) * 256 + t;       // 0..2047
    if (tt < H) x1[tt] = h2[tt];
    else {
      int j = tt - H;
      x1[3072 + j] = emb[(long)w[0] * 1024 + j];
    }
  } else {
    // vbar: block bb covers 32 cols; thread: col = bb*32 + (t&31), row-chunk t>>5 (8 x 72)
    __shared__ float red[8][32];
    int bb = b - 1096;                   // 0..63
    int c = bb * 32 + (t & 31);
    int rc = t >> 5;
    float s = 0.f;
    for (int r = rc * 72; r < rc * 72 + 72; r++) s += V[(long)r * IMG + c];
    red[rc][t & 31] = s;
    __syncthreads();
    if (t < 32) {
      float tot = 0.f;
      #pragma unroll
      for (int j = 0; j < 8; j++) tot += red[j][t];
      x1[H + bb * 32 + t] = tot * (1.0f / 576.0f);
    }
  }
}

// ---- vt GEMM via MFMA bf16: grid (9,8,4); 64x64 tile/block, 2x2 waves of 32x32 ----
__global__ __launch_bounds__(256) void k_vt_mfma(const u16* __restrict__ Vbf,
                                                 const u16* __restrict__ Wbf,
                                                 float* __restrict__ vtp) {
  int t = threadIdx.x;
  int wave = t >> 6, lane = t & 63;
  int wm = wave >> 1, wn = wave & 1;
  int m0 = blockIdx.x * 64 + wm * 32;
  int n0 = blockIdx.y * 64 + wn * 32;
  int z  = blockIdx.z;                 // K-chunk 512
  int ri = lane & 15, quad = lane >> 4;
  const u16* aptr0 = Vbf + (long)(m0 + ri) * IMG + z * 512 + quad * 8;
  const u16* aptr1 = aptr0 + 16 * IMG;
  const u16* bptr0 = Wbf + (long)(n0 + ri) * IMG + z * 512 + quad * 8;
  const u16* bptr1 = bptr0 + 16 * IMG;
  f32x4 acc00 = {0.f,0.f,0.f,0.f}, acc01 = {0.f,0.f,0.f,0.f};
  f32x4 acc10 = {0.f,0.f,0.f,0.f}, acc11 = {0.f,0.f,0.f,0.f};
  #pragma unroll 4
  for (int ks = 0; ks < 16; ks++) {
    int ko = ks * 32;
    short8 a0 = *(const short8*)(aptr0 + ko);
    short8 a1 = *(const short8*)(aptr1 + ko);
    short8 b0 = *(const short8*)(bptr0 + ko);
    short8 b1 = *(const short8*)(bptr1 + ko);
    acc00 = __builtin_amdgcn_mfma_f32_16x16x32_bf16(a0, b0, acc00, 0, 0, 0);
    acc01 = __builtin_amdgcn_mfma_f32_16x16x32_bf16(a0, b1, acc01, 0, 0, 0);
    acc10 = __builtin_amdgcn_mfma_f32_16x16x32_bf16(a1, b0, acc10, 0, 0, 0);
    acc11 = __builtin_amdgcn_mfma_f32_16x16x32_bf16(a1, b1, acc11, 0, 0, 0);
  }
  float* base = vtp + (long)z * (NR * MID);
  #pragma unroll
  for (int r = 0; r < 4; r++) {
    int row = quad * 4 + r;
    base[(long)(m0 + row) * MID + n0 + ri]           = acc00[r];
    base[(long)(m0 + row) * MID + n0 + 16 + ri]      = acc01[r];
    base[(long)(m0 + 16 + row) * MID + n0 + ri]      = acc10[r];
    base[(long)(m0 + 16 + row) * MID + n0 + 16 + ri] = acc11[r];
  }
}

// ---- fused LSTM1: block = hidden element k; wave w computes gate row k + w*H ----
__global__ __launch_bounds__(256) void k_lstm1(const float* __restrict__ Wih,
                                               const float* __restrict__ Whh,
                                               const float* __restrict__ bih,
                                               const float* __restrict__ bhh,
                                               const float* __restrict__ x1,
                                               const float* __restrict__ h1,
                                               const float* __restrict__ c1,
                                               float* __restrict__ h1n,
                                               float* __restrict__ out_h,
                                               float* __restrict__ out_c) {
  __shared__ float gate[4];
  int w = threadIdx.x >> 6, l = threadIdx.x & 63;
  int k = blockIdx.x;
  int row = k + w * H;
  const float4* W4  = (const float4*)(Wih + (long)row * IN1);
  const float4* Wh4 = (const float4*)(Whh + (long)row * H);
  const float4* X4  = (const float4*)x1;
  const float4* H14 = (const float4*)h1;
  float acc = 0.f;
  #pragma unroll
  for (int c = 0; c < 16; c++) { int idx = c * 64 + l; acc += dot4(W4[idx], X4[idx]); }
  #pragma unroll
  for (int c = 0; c < 4; c++)  { int idx = c * 64 + l; acc += dot4(Wh4[idx], H14[idx]); }
  acc = wave_sum(acc);
  if (l == 0) gate[w] = acc + bih[row] + bhh[row];
  __syncthreads();
  if (threadIdx.x == 0) {
    float i  = sigf(gate[0]);
    float f  = sigf(gate[1]);
    float gg = tanhf(gate[2]);
    float o  = sigf(gate[3]);
    float c  = f * c1[k] + i * gg;
    float h  = o * tanhf(c);
    h1n[k] = h; out_h[k] = h; out_c[k] = c;
  }
}

// ---- h1t = lh_w @ h1n + lh_b ----
__global__ void k_h1t(const float* __restrict__ lhw, const float* __restrict__ lhb,
                      const float* __restrict__ h1n, float* __restrict__ h1t) {
  int w = threadIdx.x >> 6, l = threadIdx.x & 63;
  int row = blockIdx.x * 4 + w;
  const float4* W4 = (const float4*)(lhw + (long)row * H);
  const float4* X4 = (const float4*)h1n;
  float acc = 0.f;
  #pragma unroll
  for (int c = 0; c < 4; c++) { int idx = c * 64 + l; acc += dot4(W4[idx], X4[idx]); }
  acc = wave_sum(acc);
  if (l == 0) h1t[row] = acc + lhb[row];
}

// ---- attention logits: reads 4 vtp partials + bias inline ----
__global__ void k_att(const float* __restrict__ vtp, const float* __restrict__ lvb,
                      const float* __restrict__ h1t,
                      const float* __restrict__ attw, const float* __restrict__ attb,
                      float* __restrict__ logits) {
  int w = threadIdx.x >> 6, l = threadIdx.x & 63;
  int row = blockIdx.x * 4 + w;   // 576 rows
  const float4* A4 = (const float4*)attw;
  const float4* T4 = (const float4*)h1t;
  const float4* B4 = (const float4*)lvb;
  float acc = 0.f;
  #pragma unroll
  for (int ch = 0; ch < 2; ch++) {
    int idx = 2 * l + ch;          // float4 index within MID
    const float4* p = (const float4*)(vtp + (long)row * MID) + idx;
    float4 s = p[0];
    float4 s1 = p[NR * MID / 4];
    float4 s2 = p[2 * NR * MID / 4];
    float4 s3 = p[3 * NR * MID / 4];
    float4 bb = B4[idx], tt = T4[idx], aa = A4[idx];
    float vx = s.x + s1.x + s2.x + s3.x + bb.x + tt.x;
    float vy = s.y + s1.y + s2.y + s3.y + bb.y + tt.y;
    float vz = s.z + s1.z + s2.z + s3.z + bb.z + tt.z;
    float vw = s.w + s1.w + s2.w + s3.w + bb.w + tt.w;
    acc += tanhf(vx) * aa.x + tanhf(vy) * aa.y + tanhf(vz) * aa.z + tanhf(vw) * aa.w;
  }
  acc = wave_sum(acc);
  if (l == 0) logits[row] = acc + attb[0];
}

// ---- fused softmax + weighted sum: 8 blocks x 256 threads; block b -> cols [b*256, b*256+256) ----
__global__ __launch_bounds__(256) void k_smwv(const float* __restrict__ logits,
                                              const float* __restrict__ V,
                                              float* __restrict__ v) {
  __shared__ float arr[576];
  __shared__ float red[8];
  int t = threadIdx.x;
  int wv = t >> 6, l = t & 63;
  float x0 = logits[t];
  float x1 = logits[t + 256];
  float x2 = (t < 64) ? logits[t + 512] : -3.0e38f;
  float m = fmaxf(fmaxf(x0, x1), x2);
  #pragma unroll
  for (int off = 32; off > 0; off >>= 1) m = fmaxf(m, __shfl_down(m, off, 64));
  if (l == 0) red[wv] = m;
  __syncthreads();
  float bm = fmaxf(fmaxf(red[0], red[1]), fmaxf(red[2], red[3]));
  float e0 = __expf(x0 - bm);
  float e1 = __expf(x1 - bm);
  float e2 = (t < 64) ? __expf(x2 - bm) : 0.f;
  arr[t] = e0; arr[t + 256] = e1;
  if (t < 64) arr[t + 512] = e2;
  float s = wave_sum(e0 + e1 + e2);
  __syncthreads();              // arr fully written
  if (l == 0) red[4 + wv] = s;
  __syncthreads();
  float bsum = red[4] + red[5] + red[6] + red[7];
  float inv = 1.0f / bsum;
  int c = blockIdx.x * 256 + t;
  float acc = 0.f;
  #pragma unroll 8
  for (int r = 0; r < NR; r++) acc += arr[r] * V[(long)r * IMG + c];
  v[c] = acc * inv;
}

// ---- fused LSTM2 ----
__global__ __launch_bounds__(256) void k_lstm2(const float* __restrict__ Wih,
                                               const float* __restrict__ Whh,
                                               const float* __restrict__ bih,
                                               const float* __restrict__ bhh,
                                               const float* __restrict__ v,
                                               const float* __restrict__ h1n,
                                               const float* __restrict__ h2,
                                               const float* __restrict__ c2,
                                               float* __restrict__ h2n,
                                               float* __restrict__ out_h,
                                               float* __restrict__ out_c) {
  __shared__ float gate[4];
  int w = threadIdx.x >> 6, l = threadIdx.x & 63;
  int k = blockIdx.x;
  int row = k + w * H;
  const float4* W4  = (const float4*)(Wih + (long)row * IN2);
  const float4* Wh4 = (const float4*)(Whh + (long)row * H);
  const float4* Vv4 = (const float4*)v;
  const float4* H1n = (const float4*)h1n;
  const float4* H24 = (const float4*)h2;
  float acc = 0.f;
  #pragma unroll
  for (int c = 0; c < 8; c++) { int idx = c * 64 + l; acc += dot4(W4[idx], Vv4[idx]); }
  #pragma unroll
  for (int c = 0; c < 4; c++) { int idx = c * 64 + l; acc += dot4(W4[512 + idx], H1n[idx]); }
  #pragma unroll
  for (int c = 0; c < 4; c++) { int idx = c * 64 + l; acc += dot4(Wh4[idx], H24[idx]); }
  acc = wave_sum(acc);
  if (l == 0) gate[w] = acc + bih[row] + bhh[row];
  __syncthreads();
  if (threadIdx.x == 0) {
    float i  = sigf(gate[0]);
    float f  = sigf(gate[1]);
    float gg = tanhf(gate[2]);
    float o  = sigf(gate[3]);
    float c  = f * c2[k] + i * gg;
    float h  = o * tanhf(c);
    h2n[k] = h; out_h[k] = h; out_c[k] = c;
  }
}

// ---- output logits ----
__global__ void k_out(const float* __restrict__ linw, const float* __restrict__ linb,
                      const float* __restrict__ h2n, float* __restrict__ o) {
  int w = threadIdx.x >> 6, l = threadIdx.x & 63;
  int row = blockIdx.x * 4 + w;
  const float4* W4 = (const float4*)(linw + (long)row * H);
  const float4* X4 = (const float4*)h2n;
  float acc = 0.f;
  #pragma unroll
  for (int c = 0; c < 4; c++) { int idx = c * 64 + l; acc += dot4(W4[idx], X4[idx]); }
  acc = wave_sum(acc);
  if (l == 0) o[row] = acc + linb[row];
}

extern "C" void kernel_launch(void* const* d_in, const int* in_sizes, int n_in,
                              void* d_out, int out_size, void* d_ws, size_t ws_size,
                              hipStream_t stream) {
  const float* V    = (const float*)d_in[0];
  const int*   w    = (const int*)d_in[1];
  const float* h1   = (const float*)d_in[2];
  const float* c1   = (const float*)d_in[3];
  const float* h2   = (const float*)d_in[4];
  const float* c2   = (const float*)d_in[5];
  const float* emb  = (const float*)d_in[6];
  const float* Wih1 = (const float*)d_in[7];
  const float* Whh1 = (const float*)d_in[8];
  const float* bih1 = (const float*)d_in[9];
  const float* bhh1 = (const float*)d_in[10];
  const float* Wih2 = (const float*)d_in[11];
  const float* Whh2 = (const float*)d_in[12];
  const float* bih2 = (const float*)d_in[13];
  const float* bhh2 = (const float*)d_in[14];
  const float* lvw  = (const float*)d_in[15];
  const float* lvb  = (const float*)d_in[16];
  const float* lhw  = (const float*)d_in[17];
  const float* lhb  = (const float*)d_in[18];
  const float* attw = (const float*)d_in[19];
  const float* attb = (const float*)d_in[20];
  const float* linw = (const float*)d_in[21];
  const float* linb = (const float*)d_in[22];

  float* ws     = (float*)d_ws;
  float* x1     = ws;              // 4096
  float* h1n    = ws + 4096;       // 1024
  float* h1t    = ws + 5120;       // 512
  float* logits = ws + 5632;       // 576 (pad to 640)
  float* v      = ws + 6272;       // 2048
  float* h2n    = ws + 8320;       // 1024
  float* vtp    = ws + 9344;       // 4 * 294912 = 1179648
  u16*   Vbf    = (u16*)(ws + 1188992);   // 1179648 u16
  u16*   Wbf    = Vbf + VN;               // 1048576 u16

  float* out    = (float*)d_out;
  float* out_o  = out;
  float* out_h1 = out + VOCAB;
  float* out_c1 = out + VOCAB + H;
  float* out_h2 = out + VOCAB + 2 * H;
  float* out_c2 = out + VOCAB + 3 * H;

  k_prep<<<1160, 256, 0, stream>>>(V, lvw, h2, emb, w, Vbf, Wbf, x1);
  k_vt_mfma<<<dim3(9, 8, 4), 256, 0, stream>>>(Vbf, Wbf, vtp);
  k_lstm1<<<1024, 256, 0, stream>>>(Wih1, Whh1, bih1, bhh1, x1, h1, c1, h1n, out_h1, out_c1);
  k_h1t<<<128, 256, 0, stream>>>(lhw, lhb, h1n, h1t);
  k_att<<<144, 256, 0, stream>>>(vtp, lvb, h1t, attw, attb, logits);
  k_smwv<<<8, 256, 0, stream>>>(logits, V, v);
  k_lstm2<<<1024, 256, 0, stream>>>(Wih2, Whh2, bih2, bhh2, v, h1n, h2, c2, h2n, out_h2, out_c2);
  k_out<<<8000, 256, 0, stream>>>(linw, linb, h2n, out_o);
}